// Round 13
// baseline (165.780 us; speedup 1.0000x reference)
//
#include <hip/hip_runtime.h>
#include <math.h>

#define Hdim 4096
#define NE 256
#define BM 32
#define BK 32
#define NKC (Hdim / BK)          // 128 K-chunks, 64 pairs
#define PLANE_ELEMS (Hdim * NE)  // f16 elements per plane (1,048,576 = 2 MB)
#define CHUNK_ELEMS 8192         // f16 elements per K-chunk image (16 KB)

// Scales (exact powers of two; undone in epilogue):
//   W' = 64*w, X' = 16*x, m-planes additionally *2048.
//   logit = (acc0 + acc1*2^-11) * 2^-10   (mm product dropped: validated R6-R12)
#define C0 9.765625e-4f            // 2^-10
#define C1 4.76837158203125e-7f    // 2^-21

typedef _Float16 f16x8 __attribute__((ext_vector_type(8)));
typedef _Float16 f16x4 __attribute__((ext_vector_type(4)));
typedef float f32x4 __attribute__((ext_vector_type(4)));

// K-loop barrier: orders LDS writes only (lgkmcnt); vector loads (W/X register
// prefetch) stay IN FLIGHT across it — avoids __syncthreads' vmcnt(0) drain,
// which exposed full L2/HBM latency every pair (m97-stall mechanism; this
// lgkm-only form is the verified 8-phase template pattern, m201).
#define KBAR()                                               \
  {                                                          \
    asm volatile("s_waitcnt lgkmcnt(0)" ::: "memory");       \
    __builtin_amdgcn_s_barrier();                            \
  }

// ---------------------------------------------------------------------------
// W [256][4096] fp32 -> 2 f16 planes: h = f16(64w), m = f16((64w - h)*2048).
// Plane layout: [k8 0..511][n 0..255] chunks of 8 f16 (16 B): element (n,k)
// at plane + ((k/8)*256 + n)*8 + k%8 — 16 consecutive n are 256 B contiguous,
// so per-lane fragment loads below are coalesced (4 x 256 B per instruction).
// ---------------------------------------------------------------------------
__global__ __launch_bounds__(256)
void convert_w(const float* __restrict__ W, _Float16* __restrict__ pl) {
  const int id = blockIdx.x * 256 + threadIdx.x;  // 0 .. 131071
  const int k8 = id & 511;
  const int n = id >> 9;
  const float* src = W + (long)n * Hdim + k8 * 8;
  const float4 x0 = *(const float4*)src;
  const float4 x1 = *(const float4*)(src + 4);
  const float xv[8] = {x0.x, x0.y, x0.z, x0.w, x1.x, x1.y, x1.z, x1.w};
  f16x8 vh, vm;
#pragma unroll
  for (int j = 0; j < 8; ++j) {
    const float v = xv[j] * 64.f;
    const _Float16 h = (_Float16)v;
    const float r = (v - (float)h) * 2048.f;
    vh[j] = h;
    vm[j] = (_Float16)r;
  }
  const long co = ((long)k8 * NE + n) * 8;
  *(f16x8*)(pl + co) = vh;
  *(f16x8*)(pl + PLANE_ELEMS + co) = vm;
}

// ---------------------------------------------------------------------------
// Fused: logits = X @ W^T via 3-product split-f16 MFMA (hh, hm, mh), then
// top-k epilogue. R12-verified skeleton (X split-f16 in pair-dbuf LDS staged
// by all 512 threads, W fragments direct from ws planes into registers,
// 8 waves x (32 tok x 32 exp), 2 blk/CU / 16 waves/CU, 64 chunk-pair phases)
// with ONE change: in-loop barriers are lgkm-only (KBAR) so W/X prefetch
// loads are never drained by the barrier.
// LDS 36 KB: X pair-bufs 2x8 KB @0; epilogue lg [32][260] f32 aliases smem.
// ---------------------------------------------------------------------------
__global__ __launch_bounds__(512, 4)
void moe_gate_fused(const float* __restrict__ X, const _Float16* __restrict__ pl,
                    const float* __restrict__ bias, float* __restrict__ out, int T) {
  __shared__ __align__(16) unsigned char smem[36864];
  const int tid = threadIdx.x;
  const int lane = tid & 63, wave = tid >> 6;      // wave = wn (0..7)
  const int r16 = lane & 15, c4 = lane >> 4;
  const long bm0 = (long)blockIdx.x * BM;

  f32x4 acc0[2][2], acc1[2][2];
#pragma unroll
  for (int i = 0; i < 2; ++i)
#pragma unroll
    for (int j = 0; j < 2; ++j) {
      acc0[i][j] = (f32x4)(0.f);
      acc1[i][j] = (f32x4)(0.f);
    }

  // X staging geometry: 512 threads -> (token xm 0..31, pair-slot xf 0..15)
  // sub-chunk sc = xf>>3, within-chunk float4 slot f4 = xf&7
  const int xm = tid >> 4;
  const int xf = tid & 15;
  const float* xsrc = X + (bm0 + xm) * (long)Hdim + xf * 4;  // + pair*64
  const int xws = (xf >> 3) * 4096 +                       // sub-chunk
                  (((xf & 7) >> 1) * 32 + xm) * 16 + (xf & 1) * 8;  // in-plane

  // per-lane W-fragment sources (chunk image offset (c4*256 + n)*8)
  const _Float16* wsrc0 = pl + ((size_t)(c4 * 256 + wave * 32 + r16)) * 8;
  const _Float16* wsrc1 = wsrc0 + PLANE_ELEMS;

  f16x8 wA[2][2], wB[2][2], wC[2][2], wD[2][2];   // [plane][fn]

#define LOADW(dst, kc_)                                                         \
  {                                                                             \
    const size_t ko = (size_t)(kc_) * CHUNK_ELEMS;                              \
    _Pragma("unroll") for (int fn = 0; fn < 2; ++fn) {                          \
      dst[0][fn] = *(const f16x8*)(wsrc0 + ko + fn * 128);                      \
      dst[1][fn] = *(const f16x8*)(wsrc1 + ko + fn * 128);                      \
    }                                                                           \
  }

#define WRITE_X2(b, xr)                                                         \
  {                                                                             \
    f16x4 vh, vm;                                                               \
    const float xa[4] = {(xr).x, (xr).y, (xr).z, (xr).w};                       \
    _Pragma("unroll") for (int j = 0; j < 4; ++j) {                             \
      const float v = xa[j] * 16.f;                                             \
      const _Float16 h = (_Float16)v;                                           \
      const float r = (v - (float)h) * 2048.f;                                  \
      vh[j] = h;                                                                \
      vm[j] = (_Float16)r;                                                      \
    }                                                                           \
    const int xo = (b) * 8192 + xws;                                            \
    *(f16x4*)&smem[xo] = vh;                                                    \
    *(f16x4*)&smem[xo + 2048] = vm;                                             \
  }

#define COMPUTE(b, sc, wreg)                                                    \
  {                                                                             \
    const int xo = (b) * 8192 + (sc) * 4096;                                    \
    f16x8 af[2][2];                                                             \
    _Pragma("unroll") for (int p = 0; p < 2; ++p)                               \
        _Pragma("unroll") for (int fm = 0; fm < 2; ++fm)                        \
            af[p][fm] = *(const f16x8*)&smem[xo + p * 2048 +                    \
                                             (c4 * 32 + fm * 16 + r16) * 16];   \
    _Pragma("unroll") for (int fm = 0; fm < 2; ++fm)                            \
        _Pragma("unroll") for (int fn = 0; fn < 2; ++fn) {                      \
      acc0[fm][fn] = __builtin_amdgcn_mfma_f32_16x16x32_f16(                    \
          af[0][fm], wreg[0][fn], acc0[fm][fn], 0, 0, 0);                       \
      f32x4 s = acc1[fm][fn];                                                   \
      s = __builtin_amdgcn_mfma_f32_16x16x32_f16(af[0][fm], wreg[1][fn], s, 0, 0, 0); \
      s = __builtin_amdgcn_mfma_f32_16x16x32_f16(af[1][fm], wreg[0][fn], s, 0, 0, 0); \
      acc1[fm][fn] = s;                                                         \
    }                                                                           \
  }

  // prologue: X pair 0 into buf 0; W chunks 0,1 into wA,wB
  {
    const float4 x0 = *(const float4*)(xsrc);
    WRITE_X2(0, x0);
  }
  LOADW(wA, 0);
  LOADW(wB, 1);
  __syncthreads();

  for (int p = 0; p < NKC / 2; p += 2) {
    {  // even pair p: buf0, wA/wB; prefetch X pair p+1 -> buf1, W -> wC,wD
      const float4 xn = *(const float4*)(xsrc + (size_t)(p + 1) * 64);
      LOADW(wC, 2 * p + 2);
      LOADW(wD, 2 * p + 3);
      COMPUTE(0, 0, wA);
      COMPUTE(0, 1, wB);
      WRITE_X2(1, xn);
      KBAR();
    }
    {  // odd pair p+1: buf1, wC/wD; prefetch pair p+2 (clamped tail)
      const int pn = (p + 2 < NKC / 2) ? p + 2 : NKC / 2 - 1;
      const float4 xn = *(const float4*)(xsrc + (size_t)pn * 64);
      LOADW(wA, 2 * pn);
      LOADW(wB, 2 * pn + 1);
      COMPUTE(1, 0, wC);
      COMPUTE(1, 1, wD);
      if (p + 2 < NKC / 2) WRITE_X2(0, xn);
      KBAR();
    }
  }

  // ---- epilogue: logits -> LDS [32][260] fp32, then fused top-k ----
  __syncthreads();  // full drain before aliasing smem with lg
  float* lg = (float*)smem;
#pragma unroll
  for (int fm = 0; fm < 2; ++fm)
#pragma unroll
    for (int fn = 0; fn < 2; ++fn)
#pragma unroll
      for (int r = 0; r < 4; ++r) {
        const int t = fm * 16 + c4 * 4 + r;
        const int n = wave * 32 + fn * 16 + r16;
        lg[t * 260 + n] = fmaf(acc1[fm][fn][r], C1, acc0[fm][fn][r] * C0);
      }
  __syncthreads();

  // phase 2 (verified rounds 1-12 logic): wave processes 4 tokens sequentially
  const float4 bv = *(const float4*)(bias + lane * 4);
  for (int i = 0; i < 4; ++i) {
    const int t = wave * 4 + i;
    const float4 lgv = *(const float4*)&lg[t * 260 + lane * 4];

    const float s0 = 1.f / (1.f + expf(-lgv.x));
    const float s1 = 1.f / (1.f + expf(-lgv.y));
    const float s2 = 1.f / (1.f + expf(-lgv.z));
    const float s3 = 1.f / (1.f + expf(-lgv.w));

    const float c0 = s0 + bv.x, c1 = s1 + bv.y, c2 = s2 + bv.z, c3 = s3 + bv.w;

    // lane-local top2 of 4
    float m1 = fmaxf(c0, c1), m2 = fminf(c0, c1);
    if (c2 > m1) { m2 = m1; m1 = c2; } else m2 = fmaxf(m2, c2);
    if (c3 > m1) { m2 = m1; m1 = c3; } else m2 = fmaxf(m2, c3);
#pragma unroll
    for (int off = 1; off < 8; off <<= 1) {
      const float o1 = __shfl_xor(m1, off);
      const float o2 = __shfl_xor(m2, off);
      if (o1 > m1) { m2 = fmaxf(m1, o2); m1 = o1; }
      else m2 = fmaxf(m2, o1);
    }
    const float gs = m1 + m2;  // group score (identical across the 8 lanes)

    const int gme = lane >> 3;
    int rank = 0;
#pragma unroll
    for (int j = 0; j < 8; ++j) {
      const float gj = __shfl(gs, j * 8);
      rank += ((gj > gs) || (gj == gs && j < gme)) ? 1 : 0;
    }
    const bool sel = rank < 4;

    const float NEG = -INFINITY;
    float q0 = sel ? c0 : NEG, q1 = sel ? c1 : NEG;
    float q2 = sel ? c2 : NEG, q3 = sel ? c3 : NEG;

    float sum = 0.f;
    int my_e = 0;
    float my_w = 0.f;
#pragma unroll
    for (int r = 0; r < 8; ++r) {
      float v = q0; int ix = 0;
      if (q1 > v) { v = q1; ix = 1; }
      if (q2 > v) { v = q2; ix = 2; }
      if (q3 > v) { v = q3; ix = 3; }
      int e = lane * 4 + ix;
#pragma unroll
      for (int off = 1; off < 64; off <<= 1) {
        const float v2 = __shfl_xor(v, off);
        const int e2 = __shfl_xor(e, off);
        const bool take = (v2 > v) || (v2 == v && e2 < e);
        v = take ? v2 : v;
        e = take ? e2 : e;
      }
      const int slot = e & 3, owner = e >> 2;
      const float svs = (slot == 0) ? s0 : ((slot == 1) ? s1 : ((slot == 2) ? s2 : s3));
      const float wgt = __shfl(svs, owner);
      sum += wgt;
      if (lane == r) { my_e = e; my_w = wgt; }
      const bool own = (lane == owner);
      q0 = (own && slot == 0) ? NEG : q0;
      q1 = (own && slot == 1) ? NEG : q1;
      q2 = (own && slot == 2) ? NEG : q2;
      q3 = (own && slot == 3) ? NEG : q3;
    }

    if (lane < 8) {
      const float denom = sum + 1e-20f;
      const long tg = bm0 + t;
      out[tg * 8 + lane] = (float)my_e;
      out[(long)T * 8 + tg * 8 + lane] = my_w / denom * 2.5f;
    }
  }
}

// ---------------------------------------------------------------------------
extern "C" void kernel_launch(void* const* d_in, const int* in_sizes, int n_in,
                              void* d_out, int out_size, void* d_ws, size_t ws_size,
                              hipStream_t stream) {
  const float* X = (const float*)d_in[0];   // [T, 4096]
  const float* W = (const float*)d_in[1];   // [256, 4096]
  const float* B = (const float*)d_in[2];   // [256]
  float* out = (float*)d_out;
  const int T = in_sizes[0] / Hdim;         // 16384

  _Float16* planes = (_Float16*)d_ws;       // 2 x 2 MB = 4 MB scratch

  convert_w<<<512, 256, 0, stream>>>(W, planes);
  moe_gate_fused<<<T / BM, 512, 0, stream>>>(X, planes, B, out, T);
}

// Round 14
// 162.565 us; speedup vs baseline: 1.0198x; 1.0198x over previous
//
#include <hip/hip_runtime.h>
#include <math.h>

#define Hdim 4096
#define NE 256
#define BM 32
#define BK 32
#define NKC (Hdim / BK)          // 128 K-chunks, 64 pairs
#define PLANE_ELEMS (Hdim * NE)  // f16 elements per plane (1,048,576 = 2 MB)
#define CHUNK_ELEMS 8192         // f16 elements per K-chunk image (16 KB)

// Scales (exact powers of two; undone in epilogue):
//   W' = 64*w, X' = 16*x, m-planes additionally *2048.
//   logit = (acc0 + acc1*2^-11) * 2^-10   (mm product dropped: validated R6-R13)
#define C0 9.765625e-4f            // 2^-10
#define C1 4.76837158203125e-7f    // 2^-21

typedef _Float16 f16x8 __attribute__((ext_vector_type(8)));
typedef _Float16 f16x4 __attribute__((ext_vector_type(4)));
typedef float f32x4 __attribute__((ext_vector_type(4)));

// K-loop barrier: orders LDS writes only (lgkmcnt); vector loads (W/X register
// prefetch) stay IN FLIGHT across it (verified R13: correct, neutral).
#define KBAR()                                               \
  {                                                          \
    asm volatile("s_waitcnt lgkmcnt(0)" ::: "memory");       \
    __builtin_amdgcn_s_barrier();                            \
  }

// ---------------------------------------------------------------------------
// W [256][4096] fp32 -> 2 f16 planes: h = f16(64w), m = f16((64w - h)*2048).
// Plane layout: [k8 0..511][n 0..255] chunks of 8 f16 (16 B): element (n,k)
// at plane + ((k/8)*256 + n)*8 + k%8 — 16 consecutive n are 256 B contiguous,
// so per-lane fragment loads below are coalesced (4 x 256 B per instruction).
// ---------------------------------------------------------------------------
__global__ __launch_bounds__(256)
void convert_w(const float* __restrict__ W, _Float16* __restrict__ pl) {
  const int id = blockIdx.x * 256 + threadIdx.x;  // 0 .. 131071
  const int k8 = id & 511;
  const int n = id >> 9;
  const float* src = W + (long)n * Hdim + k8 * 8;
  const float4 x0 = *(const float4*)src;
  const float4 x1 = *(const float4*)(src + 4);
  const float xv[8] = {x0.x, x0.y, x0.z, x0.w, x1.x, x1.y, x1.z, x1.w};
  f16x8 vh, vm;
#pragma unroll
  for (int j = 0; j < 8; ++j) {
    const float v = xv[j] * 64.f;
    const _Float16 h = (_Float16)v;
    const float r = (v - (float)h) * 2048.f;
    vh[j] = h;
    vm[j] = (_Float16)r;
  }
  const long co = ((long)k8 * NE + n) * 8;
  *(f16x8*)(pl + co) = vh;
  *(f16x8*)(pl + PLANE_ELEMS + co) = vm;
}

// ---------------------------------------------------------------------------
// Fused: logits = X @ W^T via 3-product split-f16 MFMA (hh, hm, mh), then
// top-k epilogue. R13-verified skeleton (X split-f16 in pair-dbuf LDS staged
// by all 512 threads, W fragments direct from ws planes into registers,
// 8 waves x (32 tok x 32 exp), 2 blk/CU / 16 waves/CU, 64 chunk-pair phases,
// lgkm-only in-loop barriers) + ONE change: sched_barrier(0) pins each
// half-pair's prefetch cluster (W chunk loads + X load) BEFORE the MFMA
// region, so the scheduler cannot sink the loads to their use sites.
// R13's VGPR_Count=48 proved the declared register double-buffer was
// collapsed: loads were issued at use, exposing full L2 latency per pair.
// LDS 36 KB: X pair-bufs 2x8 KB @0; epilogue lg [32][260] f32 aliases smem.
// ---------------------------------------------------------------------------
__global__ __launch_bounds__(512, 4)
void moe_gate_fused(const float* __restrict__ X, const _Float16* __restrict__ pl,
                    const float* __restrict__ bias, float* __restrict__ out, int T) {
  __shared__ __align__(16) unsigned char smem[36864];
  const int tid = threadIdx.x;
  const int lane = tid & 63, wave = tid >> 6;      // wave = wn (0..7)
  const int r16 = lane & 15, c4 = lane >> 4;
  const long bm0 = (long)blockIdx.x * BM;

  f32x4 acc0[2][2], acc1[2][2];
#pragma unroll
  for (int i = 0; i < 2; ++i)
#pragma unroll
    for (int j = 0; j < 2; ++j) {
      acc0[i][j] = (f32x4)(0.f);
      acc1[i][j] = (f32x4)(0.f);
    }

  // X staging geometry: 512 threads -> (token xm 0..31, pair-slot xf 0..15)
  // sub-chunk sc = xf>>3, within-chunk float4 slot f4 = xf&7
  const int xm = tid >> 4;
  const int xf = tid & 15;
  const float* xsrc = X + (bm0 + xm) * (long)Hdim + xf * 4;  // + pair*64
  const int xws = (xf >> 3) * 4096 +                       // sub-chunk
                  (((xf & 7) >> 1) * 32 + xm) * 16 + (xf & 1) * 8;  // in-plane

  // per-lane W-fragment sources (chunk image offset (c4*256 + n)*8)
  const _Float16* wsrc0 = pl + ((size_t)(c4 * 256 + wave * 32 + r16)) * 8;
  const _Float16* wsrc1 = wsrc0 + PLANE_ELEMS;

  f16x8 wA[2][2], wB[2][2], wC[2][2], wD[2][2];   // [plane][fn]

#define LOADW(dst, kc_)                                                         \
  {                                                                             \
    const size_t ko = (size_t)(kc_) * CHUNK_ELEMS;                              \
    _Pragma("unroll") for (int fn = 0; fn < 2; ++fn) {                          \
      dst[0][fn] = *(const f16x8*)(wsrc0 + ko + fn * 128);                      \
      dst[1][fn] = *(const f16x8*)(wsrc1 + ko + fn * 128);                      \
    }                                                                           \
  }

#define WRITE_X2(b, xr)                                                         \
  {                                                                             \
    f16x4 vh, vm;                                                               \
    const float xa[4] = {(xr).x, (xr).y, (xr).z, (xr).w};                       \
    _Pragma("unroll") for (int j = 0; j < 4; ++j) {                             \
      const float v = xa[j] * 16.f;                                             \
      const _Float16 h = (_Float16)v;                                           \
      const float r = (v - (float)h) * 2048.f;                                  \
      vh[j] = h;                                                                \
      vm[j] = (_Float16)r;                                                      \
    }                                                                           \
    const int xo = (b) * 8192 + xws;                                            \
    *(f16x4*)&smem[xo] = vh;                                                    \
    *(f16x4*)&smem[xo + 2048] = vm;                                             \
  }

#define COMPUTE(b, sc, wreg)                                                    \
  {                                                                             \
    const int xo = (b) * 8192 + (sc) * 4096;                                    \
    f16x8 af[2][2];                                                             \
    _Pragma("unroll") for (int p = 0; p < 2; ++p)                               \
        _Pragma("unroll") for (int fm = 0; fm < 2; ++fm)                        \
            af[p][fm] = *(const f16x8*)&smem[xo + p * 2048 +                    \
                                             (c4 * 32 + fm * 16 + r16) * 16];   \
    _Pragma("unroll") for (int fm = 0; fm < 2; ++fm)                            \
        _Pragma("unroll") for (int fn = 0; fn < 2; ++fn) {                      \
      acc0[fm][fn] = __builtin_amdgcn_mfma_f32_16x16x32_f16(                    \
          af[0][fm], wreg[0][fn], acc0[fm][fn], 0, 0, 0);                       \
      f32x4 s = acc1[fm][fn];                                                   \
      s = __builtin_amdgcn_mfma_f32_16x16x32_f16(af[0][fm], wreg[1][fn], s, 0, 0, 0); \
      s = __builtin_amdgcn_mfma_f32_16x16x32_f16(af[1][fm], wreg[0][fn], s, 0, 0, 0); \
      acc1[fm][fn] = s;                                                         \
    }                                                                           \
  }

  // prologue: X pair 0 into buf 0; W chunks 0,1 into wA,wB
  {
    const float4 x0 = *(const float4*)(xsrc);
    WRITE_X2(0, x0);
  }
  LOADW(wA, 0);
  LOADW(wB, 1);
  __syncthreads();

  for (int p = 0; p < NKC / 2; p += 2) {
    {  // even pair p: buf0, wA/wB; prefetch X pair p+1 -> buf1, W -> wC,wD
      const float4 xn = *(const float4*)(xsrc + (size_t)(p + 1) * 64);
      LOADW(wC, 2 * p + 2);
      LOADW(wD, 2 * p + 3);
      __builtin_amdgcn_sched_barrier(0);  // pin prefetch issue before MFMAs
      COMPUTE(0, 0, wA);
      COMPUTE(0, 1, wB);
      WRITE_X2(1, xn);
      KBAR();
    }
    {  // odd pair p+1: buf1, wC/wD; prefetch pair p+2 (clamped tail)
      const int pn = (p + 2 < NKC / 2) ? p + 2 : NKC / 2 - 1;
      const float4 xn = *(const float4*)(xsrc + (size_t)pn * 64);
      LOADW(wA, 2 * pn);
      LOADW(wB, 2 * pn + 1);
      __builtin_amdgcn_sched_barrier(0);  // pin prefetch issue before MFMAs
      COMPUTE(1, 0, wC);
      COMPUTE(1, 1, wD);
      if (p + 2 < NKC / 2) WRITE_X2(0, xn);
      KBAR();
    }
  }

  // ---- epilogue: logits -> LDS [32][260] fp32, then fused top-k ----
  __syncthreads();  // full drain before aliasing smem with lg
  float* lg = (float*)smem;
#pragma unroll
  for (int fm = 0; fm < 2; ++fm)
#pragma unroll
    for (int fn = 0; fn < 2; ++fn)
#pragma unroll
      for (int r = 0; r < 4; ++r) {
        const int t = fm * 16 + c4 * 4 + r;
        const int n = wave * 32 + fn * 16 + r16;
        lg[t * 260 + n] = fmaf(acc1[fm][fn][r], C1, acc0[fm][fn][r] * C0);
      }
  __syncthreads();

  // phase 2 (verified rounds 1-13 logic): wave processes 4 tokens sequentially
  const float4 bv = *(const float4*)(bias + lane * 4);
  for (int i = 0; i < 4; ++i) {
    const int t = wave * 4 + i;
    const float4 lgv = *(const float4*)&lg[t * 260 + lane * 4];

    const float s0 = 1.f / (1.f + expf(-lgv.x));
    const float s1 = 1.f / (1.f + expf(-lgv.y));
    const float s2 = 1.f / (1.f + expf(-lgv.z));
    const float s3 = 1.f / (1.f + expf(-lgv.w));

    const float c0 = s0 + bv.x, c1 = s1 + bv.y, c2 = s2 + bv.z, c3 = s3 + bv.w;

    // lane-local top2 of 4
    float m1 = fmaxf(c0, c1), m2 = fminf(c0, c1);
    if (c2 > m1) { m2 = m1; m1 = c2; } else m2 = fmaxf(m2, c2);
    if (c3 > m1) { m2 = m1; m1 = c3; } else m2 = fmaxf(m2, c3);
#pragma unroll
    for (int off = 1; off < 8; off <<= 1) {
      const float o1 = __shfl_xor(m1, off);
      const float o2 = __shfl_xor(m2, off);
      if (o1 > m1) { m2 = fmaxf(m1, o2); m1 = o1; }
      else m2 = fmaxf(m2, o1);
    }
    const float gs = m1 + m2;  // group score (identical across the 8 lanes)

    const int gme = lane >> 3;
    int rank = 0;
#pragma unroll
    for (int j = 0; j < 8; ++j) {
      const float gj = __shfl(gs, j * 8);
      rank += ((gj > gs) || (gj == gs && j < gme)) ? 1 : 0;
    }
    const bool sel = rank < 4;

    const float NEG = -INFINITY;
    float q0 = sel ? c0 : NEG, q1 = sel ? c1 : NEG;
    float q2 = sel ? c2 : NEG, q3 = sel ? c3 : NEG;

    float sum = 0.f;
    int my_e = 0;
    float my_w = 0.f;
#pragma unroll
    for (int r = 0; r < 8; ++r) {
      float v = q0; int ix = 0;
      if (q1 > v) { v = q1; ix = 1; }
      if (q2 > v) { v = q2; ix = 2; }
      if (q3 > v) { v = q3; ix = 3; }
      int e = lane * 4 + ix;
#pragma unroll
      for (int off = 1; off < 64; off <<= 1) {
        const float v2 = __shfl_xor(v, off);
        const int e2 = __shfl_xor(e, off);
        const bool take = (v2 > v) || (v2 == v && e2 < e);
        v = take ? v2 : v;
        e = take ? e2 : e;
      }
      const int slot = e & 3, owner = e >> 2;
      const float svs = (slot == 0) ? s0 : ((slot == 1) ? s1 : ((slot == 2) ? s2 : s3));
      const float wgt = __shfl(svs, owner);
      sum += wgt;
      if (lane == r) { my_e = e; my_w = wgt; }
      const bool own = (lane == owner);
      q0 = (own && slot == 0) ? NEG : q0;
      q1 = (own && slot == 1) ? NEG : q1;
      q2 = (own && slot == 2) ? NEG : q2;
      q3 = (own && slot == 3) ? NEG : q3;
    }

    if (lane < 8) {
      const float denom = sum + 1e-20f;
      const long tg = bm0 + t;
      out[tg * 8 + lane] = (float)my_e;
      out[(long)T * 8 + tg * 8 + lane] = my_w / denom * 2.5f;
    }
  }
}

// ---------------------------------------------------------------------------
extern "C" void kernel_launch(void* const* d_in, const int* in_sizes, int n_in,
                              void* d_out, int out_size, void* d_ws, size_t ws_size,
                              hipStream_t stream) {
  const float* X = (const float*)d_in[0];   // [T, 4096]
  const float* W = (const float*)d_in[1];   // [256, 4096]
  const float* B = (const float*)d_in[2];   // [256]
  float* out = (float*)d_out;
  const int T = in_sizes[0] / Hdim;         // 16384

  _Float16* planes = (_Float16*)d_ws;       // 2 x 2 MB = 4 MB scratch

  convert_w<<<512, 256, 0, stream>>>(W, planes);
  moe_gate_fused<<<T / BM, 512, 0, stream>>>(X, planes, B, out, T);
}

// Round 15
// 155.284 us; speedup vs baseline: 1.0676x; 1.0469x over previous
//
#include <hip/hip_runtime.h>
#include <math.h>

#define Hdim 4096
#define NE 256
#define BM 64
#define BK 32
#define NKC (Hdim / BK)          // 128 K-chunks, 64 pairs
#define PLANE_ELEMS (Hdim * NE)  // f16 elements per plane (1,048,576 = 2 MB)
#define CHUNK_ELEMS 8192         // f16 elements per K-chunk image (16 KB)

// Scales (exact powers of two; undone in epilogue):
//   W' = 64*w, X' = 16*x, m-planes additionally *2048.
//   logit = (acc0 + acc1*2^-11) * 2^-10   (mm product dropped: validated R6-R14)
#define C0 9.765625e-4f            // 2^-10
#define C1 4.76837158203125e-7f    // 2^-21

typedef _Float16 f16x8 __attribute__((ext_vector_type(8)));
typedef _Float16 f16x4 __attribute__((ext_vector_type(4)));
typedef float f32x4 __attribute__((ext_vector_type(4)));

// lgkm-only barrier: orders LDS writes; register-held global prefetch stays
// in flight across it (R13/R14-verified correct).
#define KBAR()                                               \
  {                                                          \
    asm volatile("s_waitcnt lgkmcnt(0)" ::: "memory");       \
    __builtin_amdgcn_s_barrier();                            \
  }

// ---------------------------------------------------------------------------
// W [256][4096] fp32 -> 2 f16 planes: h = f16(64w), m = f16((64w - h)*2048).
// Plane layout: [k8 0..511][n 0..255] chunks of 8 f16 (16 B) — per-lane
// fragment loads are coalesced (16 consecutive n = 256 B contiguous).
// ---------------------------------------------------------------------------
__global__ __launch_bounds__(256)
void convert_w(const float* __restrict__ W, _Float16* __restrict__ pl) {
  const int id = blockIdx.x * 256 + threadIdx.x;  // 0 .. 131071
  const int k8 = id & 511;
  const int n = id >> 9;
  const float* src = W + (long)n * Hdim + k8 * 8;
  const float4 x0 = *(const float4*)src;
  const float4 x1 = *(const float4*)(src + 4);
  const float xv[8] = {x0.x, x0.y, x0.z, x0.w, x1.x, x1.y, x1.z, x1.w};
  f16x8 vh, vm;
#pragma unroll
  for (int j = 0; j < 8; ++j) {
    const float v = xv[j] * 64.f;
    const _Float16 h = (_Float16)v;
    const float r = (v - (float)h) * 2048.f;
    vh[j] = h;
    vm[j] = (_Float16)r;
  }
  const long co = ((long)k8 * NE + n) * 8;
  *(f16x8*)(pl + co) = vh;
  *(f16x8*)(pl + PLANE_ELEMS + co) = vm;
}

// ---------------------------------------------------------------------------
// Fused: logits = X @ W^T via 3-product split-f16 MFMA, then top-k epilogue.
// NEW geometry (demand-ledger optimum): BM=64, grid=256 (1 block/CU), 512 thr
// = 8 waves, wave w = ALL 64 tokens x 32 DISTINCT experts (fm=4, fn=2):
//   - W fetched exactly once per CU per chunk (32 KB, was 64 KB): L2 demand
//     halved. W register pair-buffers, prefetch pinned via sched_barrier
//     (R14-verified to hold registers).
//   - X in pair-dbuf LDS (2 x 16 KB), staged by all 512 threads.
//   - lgkm-only in-loop barriers; global loads never drained by barrier.
// LDS 65 KB: X bufs 32 KB @0 (K-loop); epilogue lg [64][260] f32 (66.5 KB).
// ---------------------------------------------------------------------------
__global__ __launch_bounds__(512, 2)
void moe_gate_fused(const float* __restrict__ X, const _Float16* __restrict__ pl,
                    const float* __restrict__ bias, float* __restrict__ out, int T) {
  __shared__ __align__(16) unsigned char smem[66560];
  const int tid = threadIdx.x;
  const int lane = tid & 63, wave = tid >> 6;      // wave = expert group (0..7)
  const int r16 = lane & 15, c4 = lane >> 4;
  const long bm0 = (long)blockIdx.x * BM;

  f32x4 acc0[4][2], acc1[4][2];
#pragma unroll
  for (int i = 0; i < 4; ++i)
#pragma unroll
    for (int j = 0; j < 2; ++j) {
      acc0[i][j] = (f32x4)(0.f);
      acc1[i][j] = (f32x4)(0.f);
    }

  // X staging geometry: 512 threads -> (token xm 0..63, f4-slot 0..7);
  // each thread stages BOTH sub-chunks of a pair at (xm, f4).
  const int xm = tid >> 3;
  const int f4 = tid & 7;
  const float* xsrc = X + (bm0 + xm) * (long)Hdim + f4 * 4;  // + pair*64 + sc*32
  const int k8w = f4 >> 1, hw = f4 & 1;
  const int xws = k8w * 1024 + xm * 16 + hw * 8;  // within (sc, plane) region

  // per-lane W-fragment sources: expert n = wave*32 + fn*16 + r16, k8 = c4
  const _Float16* wsrc0 = pl + ((size_t)(c4 * 256 + wave * 32 + r16)) * 8;
  const _Float16* wsrc1 = wsrc0 + PLANE_ELEMS;

  f16x8 wA[2][2][2], wB[2][2][2];   // [chunk-in-pair][plane][fn]

#define LOADW(dst, pair_)                                                       \
  {                                                                             \
    _Pragma("unroll") for (int sc = 0; sc < 2; ++sc) {                          \
      const size_t ko = (size_t)((pair_) * 2 + sc) * CHUNK_ELEMS;               \
      _Pragma("unroll") for (int fn = 0; fn < 2; ++fn) {                        \
        dst[sc][0][fn] = *(const f16x8*)(wsrc0 + ko + fn * 128);                \
        dst[sc][1][fn] = *(const f16x8*)(wsrc1 + ko + fn * 128);                \
      }                                                                         \
    }                                                                           \
  }

#define LOADX(pair_)                                                            \
  {                                                                             \
    xn0 = *(const float4*)(xsrc + (size_t)(pair_) * 64);                        \
    xn1 = *(const float4*)(xsrc + (size_t)(pair_) * 64 + 32);                   \
  }

#define WRITE_X2(b, xr0, xr1)                                                   \
  {                                                                             \
    _Pragma("unroll") for (int sc = 0; sc < 2; ++sc) {                          \
      const float4 xr = sc ? (xr1) : (xr0);                                     \
      f16x4 vh, vm;                                                             \
      const float xa[4] = {xr.x, xr.y, xr.z, xr.w};                             \
      _Pragma("unroll") for (int j = 0; j < 4; ++j) {                           \
        const float v = xa[j] * 16.f;                                           \
        const _Float16 h = (_Float16)v;                                         \
        const float r = (v - (float)h) * 2048.f;                                \
        vh[j] = h;                                                              \
        vm[j] = (_Float16)r;                                                    \
      }                                                                         \
      const int xo = (b) * 16384 + sc * 8192 + xws;                             \
      *(f16x4*)&smem[xo] = vh;                                                  \
      *(f16x4*)&smem[xo + 4096] = vm;                                           \
    }                                                                           \
  }

#define COMPUTE(b, sc, wreg)                                                    \
  {                                                                             \
    const int xo = (b) * 16384 + (sc) * 8192;                                   \
    f16x8 af[2][4];                                                             \
    _Pragma("unroll") for (int p = 0; p < 2; ++p)                               \
        _Pragma("unroll") for (int fm = 0; fm < 4; ++fm)                        \
            af[p][fm] = *(const f16x8*)&smem[xo + p * 4096 + c4 * 1024 +        \
                                             (fm * 16 + r16) * 16];             \
    _Pragma("unroll") for (int fm = 0; fm < 4; ++fm)                            \
        _Pragma("unroll") for (int fn = 0; fn < 2; ++fn) {                      \
      acc0[fm][fn] = __builtin_amdgcn_mfma_f32_16x16x32_f16(                    \
          af[0][fm], wreg[sc][0][fn], acc0[fm][fn], 0, 0, 0);                   \
      f32x4 s = acc1[fm][fn];                                                   \
      s = __builtin_amdgcn_mfma_f32_16x16x32_f16(af[0][fm], wreg[sc][1][fn], s, 0, 0, 0); \
      s = __builtin_amdgcn_mfma_f32_16x16x32_f16(af[1][fm], wreg[sc][0][fn], s, 0, 0, 0); \
      acc1[fm][fn] = s;                                                         \
    }                                                                           \
  }

  float4 xn0, xn1;

  // prologue: X pair 0 into buf 0; W pair 0 into wA
  LOADX(0);
  WRITE_X2(0, xn0, xn1);
  LOADW(wA, 0);
  __syncthreads();

  for (int p = 0; p < NKC / 2; p += 2) {
    {  // even pair p: buf0 + wA; prefetch pair p+1 (always valid)
      LOADX(p + 1);
      LOADW(wB, p + 1);
      __builtin_amdgcn_sched_barrier(0);  // pin prefetch issue before MFMAs
      COMPUTE(0, 0, wA);
      COMPUTE(0, 1, wA);
      WRITE_X2(1, xn0, xn1);
      KBAR();
    }
    {  // odd pair p+1: buf1 + wB; prefetch pair p+2 (clamped tail)
      const int pn = (p + 2 < NKC / 2) ? p + 2 : NKC / 2 - 1;
      LOADX(pn);
      LOADW(wA, pn);
      __builtin_amdgcn_sched_barrier(0);
      COMPUTE(1, 0, wB);
      COMPUTE(1, 1, wB);
      if (p + 2 < NKC / 2) WRITE_X2(0, xn0, xn1);
      KBAR();
    }
  }

  // ---- epilogue: logits -> LDS [64][260] fp32, then fused top-k ----
  __syncthreads();  // full drain before aliasing smem with lg
  float* lg = (float*)smem;
#pragma unroll
  for (int fm = 0; fm < 4; ++fm)
#pragma unroll
    for (int fn = 0; fn < 2; ++fn)
#pragma unroll
      for (int r = 0; r < 4; ++r) {
        const int t = fm * 16 + c4 * 4 + r;
        const int n = wave * 32 + fn * 16 + r16;
        lg[t * 260 + n] = fmaf(acc1[fm][fn][r], C1, acc0[fm][fn][r] * C0);
      }
  __syncthreads();

  // phase 2 (verified rounds 1-14 logic): wave processes 8 tokens sequentially
  const float4 bv = *(const float4*)(bias + lane * 4);
  for (int i = 0; i < 8; ++i) {
    const int t = wave * 8 + i;
    const float4 lgv = *(const float4*)&lg[t * 260 + lane * 4];

    const float s0 = 1.f / (1.f + expf(-lgv.x));
    const float s1 = 1.f / (1.f + expf(-lgv.y));
    const float s2 = 1.f / (1.f + expf(-lgv.z));
    const float s3 = 1.f / (1.f + expf(-lgv.w));

    const float c0 = s0 + bv.x, c1 = s1 + bv.y, c2 = s2 + bv.z, c3 = s3 + bv.w;

    // lane-local top2 of 4
    float m1 = fmaxf(c0, c1), m2 = fminf(c0, c1);
    if (c2 > m1) { m2 = m1; m1 = c2; } else m2 = fmaxf(m2, c2);
    if (c3 > m1) { m2 = m1; m1 = c3; } else m2 = fmaxf(m2, c3);
#pragma unroll
    for (int off = 1; off < 8; off <<= 1) {
      const float o1 = __shfl_xor(m1, off);
      const float o2 = __shfl_xor(m2, off);
      if (o1 > m1) { m2 = fmaxf(m1, o2); m1 = o1; }
      else m2 = fmaxf(m2, o1);
    }
    const float gs = m1 + m2;  // group score (identical across the 8 lanes)

    const int gme = lane >> 3;
    int rank = 0;
#pragma unroll
    for (int j = 0; j < 8; ++j) {
      const float gj = __shfl(gs, j * 8);
      rank += ((gj > gs) || (gj == gs && j < gme)) ? 1 : 0;
    }
    const bool sel = rank < 4;

    const float NEG = -INFINITY;
    float q0 = sel ? c0 : NEG, q1 = sel ? c1 : NEG;
    float q2 = sel ? c2 : NEG, q3 = sel ? c3 : NEG;

    float sum = 0.f;
    int my_e = 0;
    float my_w = 0.f;
#pragma unroll
    for (int r = 0; r < 8; ++r) {
      float v = q0; int ix = 0;
      if (q1 > v) { v = q1; ix = 1; }
      if (q2 > v) { v = q2; ix = 2; }
      if (q3 > v) { v = q3; ix = 3; }
      int e = lane * 4 + ix;
#pragma unroll
      for (int off = 1; off < 64; off <<= 1) {
        const float v2 = __shfl_xor(v, off);
        const int e2 = __shfl_xor(e, off);
        const bool take = (v2 > v) || (v2 == v && e2 < e);
        v = take ? v2 : v;
        e = take ? e2 : e;
      }
      const int slot = e & 3, owner = e >> 2;
      const float svs = (slot == 0) ? s0 : ((slot == 1) ? s1 : ((slot == 2) ? s2 : s3));
      const float wgt = __shfl(svs, owner);
      sum += wgt;
      if (lane == r) { my_e = e; my_w = wgt; }
      const bool own = (lane == owner);
      q0 = (own && slot == 0) ? NEG : q0;
      q1 = (own && slot == 1) ? NEG : q1;
      q2 = (own && slot == 2) ? NEG : q2;
      q3 = (own && slot == 3) ? NEG : q3;
    }

    if (lane < 8) {
      const float denom = sum + 1e-20f;
      const long tg = bm0 + t;
      out[tg * 8 + lane] = (float)my_e;
      out[(long)T * 8 + tg * 8 + lane] = my_w / denom * 2.5f;
    }
  }
}

// ---------------------------------------------------------------------------
extern "C" void kernel_launch(void* const* d_in, const int* in_sizes, int n_in,
                              void* d_out, int out_size, void* d_ws, size_t ws_size,
                              hipStream_t stream) {
  const float* X = (const float*)d_in[0];   // [T, 4096]
  const float* W = (const float*)d_in[1];   // [256, 4096]
  const float* B = (const float*)d_in[2];   // [256]
  float* out = (float*)d_out;
  const int T = in_sizes[0] / Hdim;         // 16384

  _Float16* planes = (_Float16*)d_ws;       // 2 x 2 MB = 4 MB scratch

  convert_w<<<512, 256, 0, stream>>>(W, planes);
  moe_gate_fused<<<T / BM, 512, 0, stream>>>(X, planes, B, out, T);
}